// Round 5
// baseline (240.242 us; speedup 1.0000x reference)
//
#include <hip/hip_runtime.h>
#include <stdint.h>

#define IN_C   128
#define OUT_C  128
#define KTOT   1152      // IN_C*3*3
#define NG     8
#define NW     8
#define NB     8
#define HH     56
#define WWID   56
#define NPIX   3136
#define PPAD   3200
#define MTOT   1024      // OUT_C*NW
#define HALO   58        // 56 + zero border on each side
#define HPIX   (HALO*HALO)   // 3364

// k-order is SPATIAL-MAJOR: k' = s*128 + c, s = kh*3+kw.
// B is gathered from zero-halo Xt[b][58*58][128c] bf16 into LDS.
// A-fragments are loaded DIRECTLY global->VGPR (L2/L1-resident), no LDS for A.

typedef __attribute__((ext_vector_type(8))) short short8;
typedef __attribute__((ext_vector_type(8))) unsigned short ushort8;
typedef __attribute__((ext_vector_type(4))) float f32x4;

__device__ __forceinline__ unsigned short f2bf(float f) {
    unsigned u = __float_as_uint(f);
    u += 0x7FFF + ((u >> 16) & 1);          // round-to-nearest-even
    return (unsigned short)(u >> 16);
}

__device__ __forceinline__ void cp16(const unsigned short* g, unsigned short* l) {
    __builtin_amdgcn_global_load_lds(
        (const __attribute__((address_space(1))) unsigned int*)g,
        (__attribute__((address_space(3))) unsigned int*)l,
        16, 0, 0);
}

// ---------- 1) fused prep: gap (blocks 0..1023) | tconv (1024..1599) | transpose (1600..1823) ----------
__global__ __launch_bounds__(256) void prep_kernel(const float* __restrict__ in,
                                                   const float* __restrict__ T,
                                                   float* __restrict__ xse,
                                                   unsigned short* __restrict__ Abf,
                                                   unsigned short* __restrict__ Xt) {
    __shared__ unsigned short tile[128 * 128];       // 32 KB (transpose); gap aliases 16 B
    const int blk = blockIdx.x;
    const int t = threadIdx.x;

    if (blk < 1024) {
        // ---- global average pool: xse[b,c] ----
        const float* src = in + (size_t)blk * NPIX;
        float s = 0.f;
        for (int i = t; i < NPIX / 4; i += 256) {
            float4 v = ((const float4*)src)[i];
            s += v.x + v.y + v.z + v.w;
        }
        #pragma unroll
        for (int off = 32; off; off >>= 1) s += __shfl_down(s, off);
        float* ws4 = (float*)tile;
        if ((t & 63) == 0) ws4[t >> 6] = s;
        __syncthreads();
        if (t == 0)
            xse[blk] = (ws4[0] + ws4[1] + ws4[2] + ws4[3]) * (1.0f / (float)NPIX);
        return;
    }
    if (blk < 1600) {
        // ---- templates -> bf16, A[m=o*8+j][k'=s*128+c] = T[(o*1152+c*9+s)*8+j] ----
        const int id = (blk - 1024) * 256 + t;       // 0..147455 exact
        const int m = id / 144;
        const int kc = id - m * 144;
        const int o = m >> 3, j = m & 7;
        const int s = kc >> 4;
        const int c0 = (kc & 15) << 3;
        ushort8 v;
        #pragma unroll
        for (int i = 0; i < 8; i++)
            v[i] = f2bf(T[((size_t)(o * KTOT + (c0 + i) * 9 + s)) * 8 + j]);
        *(ushort8*)&Abf[(size_t)m * KTOT + s * 128 + c0] = v;
        return;
    }
    // ---- transpose: in[b][c][y][x] fp32 -> Xt[b][(y+1)*58+(x+1)][c] bf16, zero halo ----
    const int idx = blk - 1600;                      // 0..223
    const int yt = idx % 28;
    const int b  = idx / 28;
    const int y0 = yt * 2;

    #pragma unroll
    for (int it = 0; it < 14; it++) {
        const int f = it * 256 + t;
        const int c = f / 28;
        const int rem = f - c * 28;
        const int y = rem / 14;
        const int x4 = rem - y * 14;
        const float4 v = *(const float4*)(in + ((size_t)(b * IN_C + c)) * NPIX
                                          + (y0 + y) * WWID + x4 * 4);
        unsigned short bf0 = f2bf(v.x), bf1 = f2bf(v.y), bf2 = f2bf(v.z), bf3 = f2bf(v.w);
        const int ppb = (y * WWID + x4 * 4) ^ (((c >> 3) & 15) << 2);
        uint2 pk;
        pk.x = (unsigned)bf0 | ((unsigned)bf1 << 16);
        pk.y = (unsigned)bf2 | ((unsigned)bf3 << 16);
        *(uint2*)&tile[c * 128 + ppb] = pk;
    }
    __syncthreads();

    #pragma unroll
    for (int it = 0; it < 7; it++) {
        const int ch = it * 256 + t;
        const int oct = ch & 15;
        const int pp = ch >> 4;
        const int sw = oct << 2;
        ushort8 v;
        #pragma unroll
        for (int i = 0; i < 8; i++)
            v[i] = tile[(oct * 8 + i) * 128 + (pp ^ sw)];
        const int y2 = (pp >= WWID) ? 1 : 0;
        const int xg = pp - y2 * WWID;
        const size_t hp = (size_t)b * HPIX + (y0 + y2 + 1) * HALO + (xg + 1);
        *(ushort8*)&Xt[hp * 128 + oct * 8] = v;
    }

    if (t < 64) {   // halo columns xx=0,57 for this block's two rows
        const int pi = t >> 4, oct = t & 15;
        const int yy = y0 + 1 + (pi >> 1);
        const int xx = (pi & 1) * 57;
        *(ushort8*)&Xt[((size_t)b * HPIX + yy * HALO + xx) * 128 + oct * 8] =
            (ushort8){0, 0, 0, 0, 0, 0, 0, 0};
    }
    if (yt == 0 || yt == 27) {   // halo rows yy=0 / 57
        const int yy = (yt == 0) ? 0 : 57;
        #pragma unroll
        for (int it = 0; it < 4; it++) {
            const int ch = it * 256 + t;
            if (ch < 928) {
                const int xx = ch >> 4, oct = ch & 15;
                *(ushort8*)&Xt[((size_t)b * HPIX + yy * HALO + xx) * 128 + oct * 8] =
                    (ushort8){0, 0, 0, 0, 0, 0, 0, 0};
            }
        }
    }
}

// ---------- 2) s_kernel (routing fused): s[b][p][j] = sum_g probs[b,g,p] * r[b,g*8+j] ----------
__global__ __launch_bounds__(256) void s_kernel(const float* __restrict__ Alpha,
                                                const int* __restrict__ mask,
                                                const float* __restrict__ xse,
                                                const float* __restrict__ rw,
                                                const float* __restrict__ rb,
                                                const int* __restrict__ use_alpha,
                                                float* __restrict__ Sws) {
    const int b = blockIdx.y;
    const int t = threadIdx.x;
    const int p = blockIdx.x * 256 + t;
    __shared__ float xs[IN_C];
    __shared__ float rsh[64];
    if (t < IN_C) xs[t] = xse[b * IN_C + t];
    __syncthreads();
    if (t < 64) {
        float acc = rb[t];
        #pragma unroll 8
        for (int c = 0; c < IN_C; c++) acc += xs[c] * rw[t * IN_C + c];
        rsh[t] = 0.25f / (1.0f + expf(-acc));        // 2*sigmoid/8
    }
    __syncthreads();
    if (p >= PPAD) return;
    float sj[8] = {0, 0, 0, 0, 0, 0, 0, 0};
    if (p < NPIX) {
        float pr[8];
        if (use_alpha[0]) {
            float a[8], m = -1e30f;
            #pragma unroll
            for (int g = 0; g < 8; g++) {
                a[g] = Alpha[((size_t)(b * NG + g)) * NPIX + p];
                m = fmaxf(m, a[g]);
            }
            float sum = 0.f;
            #pragma unroll
            for (int g = 0; g < 8; g++) { pr[g] = expf(a[g] - m); sum += pr[g]; }
            float inv = 1.f / sum;
            #pragma unroll
            for (int g = 0; g < 8; g++) pr[g] *= inv;
        } else {
            int mg = mask[(size_t)b * NPIX + p];
            #pragma unroll
            for (int g = 0; g < 8; g++) pr[g] = (g == mg) ? 1.f : 0.f;
        }
        #pragma unroll
        for (int g = 0; g < 8; g++)
            #pragma unroll
            for (int j = 0; j < 8; j++) sj[j] += pr[g] * rsh[g * 8 + j];
    }
    float* dst = Sws + ((size_t)b * PPAD + p) * 8;
    *(f32x4*)dst = (f32x4){sj[0], sj[1], sj[2], sj[3]};
    *(f32x4*)(dst + 4) = (f32x4){sj[4], sj[5], sj[6], sj[7]};
}

// ---------- 3) main GEMM + blend epilogue ----------
// A-frags direct global->VGPR (register ping-pong, k-loop unrolled x2).
// B staged via global_load_lds into 2 x 8 KB LDS buffers, one barrier per k32.
__global__ __launch_bounds__(256) void gemm_kernel(const unsigned short* __restrict__ Abf,
                                                   const unsigned short* __restrict__ Xt,
                                                   const float* __restrict__ Sws,
                                                   const float* __restrict__ bias,
                                                   float* __restrict__ out) {
    __shared__ __align__(16) unsigned short Bsh[2][512 * 8];   // 2 x 8 KB
    const int tid = threadIdx.x;
    const int wv = tid >> 6, ln = tid & 63;
    const int lq = ln >> 4, lr = ln & 15;
    const int wrow = wv >> 1, wcol = wv & 1;

    const int lid = blockIdx.x;            // 0..1599
    const int b   = lid & 7;               // XCD = b
    const int sl  = lid >> 3;              // 0..199
    const int mt  = sl & 7;
    const int nt  = sl >> 3;               // 0..24

    f32x4 acc[4][4];
    #pragma unroll
    for (int i = 0; i < 4; i++)
        #pragma unroll
        for (int j = 0; j < 4; j++) acc[i][j] = (f32x4){0.f, 0.f, 0.f, 0.f};

    // B staging: chunk ch = r*4 + qs; global octet q = qs ^ (r&3)
    const int r0 = tid >> 2,  q0 = (tid & 3) ^ (r0 & 3);
    const int r1 = r0 + 64,   q1 = (tid & 3) ^ (r1 & 3);
    const int p0 = min(nt * 128 + r0, NPIX - 1);
    const int p1 = min(nt * 128 + r1, NPIX - 1);
    const int y0p = p0 / WWID, x0p = p0 - y0p * WWID;
    const int y1p = p1 / WWID, x1p = p1 - y1p * WWID;
    const unsigned short* gb0 = Xt + ((size_t)b * HPIX + y0p * HALO + x0p) * 128 + q0 * 8;
    const unsigned short* gb1 = Xt + ((size_t)b * HPIX + y1p * HALO + x1p) * 128 + q1 * 8;
    unsigned short* lb0[2] = { &Bsh[0][(wv * 64) * 8],       &Bsh[1][(wv * 64) * 8] };
    unsigned short* lb1[2] = { &Bsh[0][(256 + wv * 64) * 8], &Bsh[1][(256 + wv * 64) * 8] };

    // A direct per-tm pointers: row m = mt*128 + wrow*64 + tm*16 + lr, k-octet lq
    const unsigned short* ga[4];
    #pragma unroll
    for (int tm = 0; tm < 4; tm++)
        ga[tm] = Abf + (size_t)(mt * 128 + wrow * 64 + tm * 16 + lr) * KTOT + lq * 8;

    // prologue: B tile 0 -> buf0; A frags for kk=0 -> afA
    cp16(gb0, lb0[0]); cp16(gb1, lb1[0]);
    short8 afA[4], afB[4];
    #pragma unroll
    for (int tm = 0; tm < 4; tm++) afA[tm] = *(const short8*)(ga[tm]);

    #pragma unroll 1
    for (int it = 0; it < 18; it++) {
        const int kk = it * 64;
        // ---- half 0: compute kk (buf0, afA); prefetch kk+32 (buf1, afB) ----
        __syncthreads();
        {
            const int nk = kk + 32;                    // always < KTOT
            const int s  = nk >> 7;
            const int kh = s / 3, kw = s - 3 * kh;
            const int offB = (kh * HALO + kw) * 128 + (nk & 127);
            cp16(gb0 + offB, lb0[1]); cp16(gb1 + offB, lb1[1]);
            #pragma unroll
            for (int tm = 0; tm < 4; tm++) afB[tm] = *(const short8*)(ga[tm] + nk);
        }
        {
            short8 bfr[4];
            #pragma unroll
            for (int tn = 0; tn < 4; tn++) {
                const int row = wcol * 64 + tn * 16 + lr;
                bfr[tn] = *(const short8*)&Bsh[0][(row * 4 + (lq ^ (lr & 3))) * 8];
            }
            #pragma unroll
            for (int tm = 0; tm < 4; tm++)
                #pragma unroll
                for (int tn = 0; tn < 4; tn++)
                    acc[tm][tn] = __builtin_amdgcn_mfma_f32_16x16x32_bf16(
                        afA[tm], bfr[tn], acc[tm][tn], 0, 0, 0);
        }
        // ---- half 1: compute kk+32 (buf1, afB); prefetch kk+64 (buf0, afA) ----
        __syncthreads();
        {
            const int nk = kk + 64;
            if (nk < KTOT) {
                const int s  = nk >> 7;
                const int kh = s / 3, kw = s - 3 * kh;
                const int offB = (kh * HALO + kw) * 128 + (nk & 127);
                cp16(gb0 + offB, lb0[0]); cp16(gb1 + offB, lb1[0]);
                #pragma unroll
                for (int tm = 0; tm < 4; tm++) afA[tm] = *(const short8*)(ga[tm] + nk);
            }
        }
        {
            short8 bfr[4];
            #pragma unroll
            for (int tn = 0; tn < 4; tn++) {
                const int row = wcol * 64 + tn * 16 + lr;
                bfr[tn] = *(const short8*)&Bsh[1][(row * 4 + (lq ^ (lr & 3))) * 8];
            }
            #pragma unroll
            for (int tm = 0; tm < 4; tm++)
                #pragma unroll
                for (int tn = 0; tn < 4; tn++)
                    acc[tm][tn] = __builtin_amdgcn_mfma_f32_16x16x32_bf16(
                        afB[tm], bfr[tn], acc[tm][tn], 0, 0, 0);
        }
    }

    // epilogue: rows m -> j = (lq&1)*4+reg, o_off = lq>>1
    const int j0 = (lq & 1) * 4;
    const int oo = lq >> 1;
    #pragma unroll
    for (int tm = 0; tm < 4; tm++) {
        const int o = mt * 16 + wrow * 8 + tm * 2 + oo;
        const float bo = bias[o];
        #pragma unroll
        for (int tn = 0; tn < 4; tn++) {
            const int p = nt * 128 + wcol * 64 + tn * 16 + lr;
            const f32x4 sv = *(const f32x4*)&Sws[((size_t)b * PPAD + p) * 8 + j0];
            const f32x4 a = acc[tm][tn];
            float part = a.x * sv.x + a.y * sv.y + a.z * sv.z + a.w * sv.w;
            float tot = part + __shfl_xor(part, 16);
            if ((lq & 1) == 0 && p < NPIX)
                out[((size_t)b * OUT_C + o) * NPIX + p] = tot + bo;
        }
    }
}

extern "C" void kernel_launch(void* const* d_in, const int* in_sizes, int n_in,
                              void* d_out, int out_size, void* d_ws, size_t ws_size,
                              hipStream_t stream) {
    const float* inputs = (const float*)d_in[0];
    const int*   mask   = (const int*)d_in[1];
    const float* Alpha  = (const float*)d_in[2];
    const float* wtmpl  = (const float*)d_in[3];
    const float* rw     = (const float*)d_in[4];
    const float* rb     = (const float*)d_in[5];
    const float* bias   = (const float*)d_in[6];
    const int*   ua     = (const int*)d_in[7];
    float* out = (float*)d_out;

    char* ws = (char*)d_ws;
    unsigned short* Xt  = (unsigned short*)ws;                  // 8*3364*128*2 = 6,889,472
    unsigned short* Abf = (unsigned short*)(ws + 6889472);      // 1024*1152*2  = 2,359,296
    float*          Sws = (float*)(ws + 9248768);               // 8*3200*8*4   =   819,200
    float*          xse = (float*)(ws + 10067968);              // 1024*4

    prep_kernel<<<1824, 256, 0, stream>>>(inputs, wtmpl, xse, Abf, Xt);
    s_kernel<<<dim3(13, NB), 256, 0, stream>>>(Alpha, mask, xse, rw, rb, ua, Sws);
    gemm_kernel<<<1600, 256, 0, stream>>>(Abf, Xt, Sws, bias, out);
}

// Round 6
// 175.955 us; speedup vs baseline: 1.3654x; 1.3654x over previous
//
#include <hip/hip_runtime.h>
#include <stdint.h>

#define IN_C   128
#define OUT_C  128
#define KTOT   1152      // IN_C*3*3
#define NG     8
#define NW     8
#define NB     8
#define HH     56
#define WWID   56
#define NPIX   3136
#define PPAD   3200
#define MTOT   1024      // OUT_C*NW
#define HALO   58        // 56 + zero border on each side
#define HPIX   (HALO*HALO)   // 3364

// k-order is SPATIAL-MAJOR: k' = s*128 + c, s = kh*3+kw.
// B gathered from zero-halo Xt[b][58*58][128c] bf16; A from repacked Abf.
// Both staged through LDS with a conflict-free XOR swizzle:
//   chunk (row r, slot j) holds global k-octet q = j ^ (r&3) ^ ((r>>2)&3).

typedef __attribute__((ext_vector_type(8))) short short8;
typedef __attribute__((ext_vector_type(8))) unsigned short ushort8;
typedef __attribute__((ext_vector_type(4))) float f32x4;

__device__ __forceinline__ unsigned short f2bf(float f) {
    unsigned u = __float_as_uint(f);
    u += 0x7FFF + ((u >> 16) & 1);          // round-to-nearest-even
    return (unsigned short)(u >> 16);
}

__device__ __forceinline__ void cp16(const unsigned short* g, unsigned short* l) {
    __builtin_amdgcn_global_load_lds(
        (const __attribute__((address_space(1))) unsigned int*)g,
        (__attribute__((address_space(3))) unsigned int*)l,
        16, 0, 0);
}

// ---------- 1) fused prep: gap (0..1023) | tconv (1024..1151) | transpose (1152..1375) ----------
__global__ __launch_bounds__(256) void prep_kernel(const float* __restrict__ in,
                                                   const float* __restrict__ T,
                                                   float* __restrict__ xse,
                                                   unsigned short* __restrict__ Abf,
                                                   unsigned short* __restrict__ Xt) {
    __shared__ __align__(16) unsigned char smem[36864];   // 36 KB
    const int blk = blockIdx.x;
    const int t = threadIdx.x;

    if (blk < 1024) {
        // ---- global average pool: xse[b,c] ----
        const float* src = in + (size_t)blk * NPIX;
        float s = 0.f;
        for (int i = t; i < NPIX / 4; i += 256) {
            float4 v = ((const float4*)src)[i];
            s += v.x + v.y + v.z + v.w;
        }
        #pragma unroll
        for (int off = 32; off; off >>= 1) s += __shfl_down(s, off);
        float* ws4 = (float*)smem;
        if ((t & 63) == 0) ws4[t >> 6] = s;
        __syncthreads();
        if (t == 0)
            xse[blk] = (ws4[0] + ws4[1] + ws4[2] + ws4[3]) * (1.0f / (float)NPIX);
        return;
    }
    if (blk < 1152) {
        // ---- tconv: block per o. Coalesced read of T[o][k][j] slab -> LDS ->
        //      Abf[m=o*8+j][k'=s*128+c] = T[(o*1152 + c*9 + s)*8 + j], coalesced writes.
        float* lf = (float*)smem;                    // 9216 floats = 36 KB
        const int o = blk - 1024;
        const float* To = T + (size_t)o * 9216;
        #pragma unroll
        for (int it = 0; it < 9; it++) {
            const int f = it * 256 + t;              // 0..2303 float4 units
            const float4 v = ((const float4*)To)[f];
            *(float4*)&lf[f * 4] = v;
        }
        __syncthreads();
        #pragma unroll
        for (int it = 0; it < 5; it++) {
            const int ch = it * 256 + t;             // 0..1151 ushort8 chunks
            if (ch < 1152) {
                const int j = ch / 144, kc = ch - j * 144;
                const int s = kc >> 4, c0 = (kc & 15) << 3;
                ushort8 v;
                #pragma unroll
                for (int i = 0; i < 8; i++)
                    v[i] = f2bf(lf[((c0 + i) * 9 + s) * 8 + j]);
                *(ushort8*)&Abf[(size_t)(o * 8 + j) * KTOT + s * 128 + c0] = v;
            }
        }
        return;
    }
    // ---- transpose: in[b][c][y][x] fp32 -> Xt[b][(y+1)*58+(x+1)][c] bf16, zero halo ----
    unsigned short* tile = (unsigned short*)smem;    // 32 KB, [c][pix 0..112)
    const int idx = blk - 1152;                      // 0..223
    const int yt = idx % 28;
    const int b  = idx / 28;
    const int y0 = yt * 2;

    #pragma unroll
    for (int it = 0; it < 14; it++) {
        const int f = it * 256 + t;
        const int c = f / 28;
        const int rem = f - c * 28;
        const int y = rem / 14;
        const int x4 = rem - y * 14;
        const float4 v = *(const float4*)(in + ((size_t)(b * IN_C + c)) * NPIX
                                          + (y0 + y) * WWID + x4 * 4);
        unsigned short bf0 = f2bf(v.x), bf1 = f2bf(v.y), bf2 = f2bf(v.z), bf3 = f2bf(v.w);
        const int ppb = (y * WWID + x4 * 4) ^ (((c >> 3) & 15) << 2);
        uint2 pk;
        pk.x = (unsigned)bf0 | ((unsigned)bf1 << 16);
        pk.y = (unsigned)bf2 | ((unsigned)bf3 << 16);
        *(uint2*)&tile[c * 128 + ppb] = pk;
    }
    __syncthreads();

    #pragma unroll
    for (int it = 0; it < 7; it++) {
        const int ch = it * 256 + t;
        const int oct = ch & 15;
        const int pp = ch >> 4;
        const int sw = oct << 2;
        ushort8 v;
        #pragma unroll
        for (int i = 0; i < 8; i++)
            v[i] = tile[(oct * 8 + i) * 128 + (pp ^ sw)];
        const int y2 = (pp >= WWID) ? 1 : 0;
        const int xg = pp - y2 * WWID;
        const size_t hp = (size_t)b * HPIX + (y0 + y2 + 1) * HALO + (xg + 1);
        *(ushort8*)&Xt[hp * 128 + oct * 8] = v;
    }

    if (t < 64) {   // halo columns xx=0,57 for this block's two rows
        const int pi = t >> 4, oct = t & 15;
        const int yy = y0 + 1 + (pi >> 1);
        const int xx = (pi & 1) * 57;
        *(ushort8*)&Xt[((size_t)b * HPIX + yy * HALO + xx) * 128 + oct * 8] =
            (ushort8){0, 0, 0, 0, 0, 0, 0, 0};
    }
    if (yt == 0 || yt == 27) {   // halo rows yy=0 / 57
        const int yy = (yt == 0) ? 0 : 57;
        #pragma unroll
        for (int it = 0; it < 4; it++) {
            const int ch = it * 256 + t;
            if (ch < 928) {
                const int xx = ch >> 4, oct = ch & 15;
                *(ushort8*)&Xt[((size_t)b * HPIX + yy * HALO + xx) * 128 + oct * 8] =
                    (ushort8){0, 0, 0, 0, 0, 0, 0, 0};
            }
        }
    }
}

// ---------- 2) s_kernel (routing fused): s[b][p][j] = sum_g probs[b,g,p] * r[b,g*8+j] ----------
__global__ __launch_bounds__(256) void s_kernel(const float* __restrict__ Alpha,
                                                const int* __restrict__ mask,
                                                const float* __restrict__ xse,
                                                const float* __restrict__ rw,
                                                const float* __restrict__ rb,
                                                const int* __restrict__ use_alpha,
                                                float* __restrict__ Sws) {
    const int b = blockIdx.y;
    const int t = threadIdx.x;
    const int p = blockIdx.x * 256 + t;
    __shared__ float xs[IN_C];
    __shared__ float rsh[64];
    if (t < IN_C) xs[t] = xse[b * IN_C + t];
    __syncthreads();
    if (t < 64) {
        float acc = rb[t];
        #pragma unroll 8
        for (int c = 0; c < IN_C; c++) acc += xs[c] * rw[t * IN_C + c];
        rsh[t] = 0.25f / (1.0f + expf(-acc));        // 2*sigmoid/8
    }
    __syncthreads();
    if (p >= PPAD) return;
    float sj[8] = {0, 0, 0, 0, 0, 0, 0, 0};
    if (p < NPIX) {
        float pr[8];
        if (use_alpha[0]) {
            float a[8], m = -1e30f;
            #pragma unroll
            for (int g = 0; g < 8; g++) {
                a[g] = Alpha[((size_t)(b * NG + g)) * NPIX + p];
                m = fmaxf(m, a[g]);
            }
            float sum = 0.f;
            #pragma unroll
            for (int g = 0; g < 8; g++) { pr[g] = expf(a[g] - m); sum += pr[g]; }
            float inv = 1.f / sum;
            #pragma unroll
            for (int g = 0; g < 8; g++) pr[g] *= inv;
        } else {
            int mg = mask[(size_t)b * NPIX + p];
            #pragma unroll
            for (int g = 0; g < 8; g++) pr[g] = (g == mg) ? 1.f : 0.f;
        }
        #pragma unroll
        for (int g = 0; g < 8; g++)
            #pragma unroll
            for (int j = 0; j < 8; j++) sj[j] += pr[g] * rsh[g * 8 + j];
    }
    float* dst = Sws + ((size_t)b * PPAD + p) * 8;
    *(f32x4*)dst = (f32x4){sj[0], sj[1], sj[2], sj[3]};
    *(f32x4*)(dst + 4) = (f32x4){sj[4], sj[5], sj[6], sj[7]};
}

// ---------- 3) main GEMM + blend epilogue ----------
// A+B staged via global_load_lds, 2x(8+8)KB double buffer, 1 barrier/k32.
// Conflict-free swizzle: slot j holds octet j ^ (r&3) ^ ((r>>2)&3).
__global__ __launch_bounds__(256) void gemm_kernel(const unsigned short* __restrict__ Abf,
                                                   const unsigned short* __restrict__ Xt,
                                                   const float* __restrict__ Sws,
                                                   const float* __restrict__ bias,
                                                   float* __restrict__ out) {
    __shared__ __align__(16) unsigned short Ash[2][512 * 8];   // 2 x 8 KB
    __shared__ __align__(16) unsigned short Bsh[2][512 * 8];   // 2 x 8 KB
    const int tid = threadIdx.x;
    const int wv = tid >> 6, ln = tid & 63;
    const int lq = ln >> 4, lr = ln & 15;
    const int wrow = wv >> 1, wcol = wv & 1;

    const int lid = blockIdx.x;            // 0..1599
    const int b   = lid & 7;               // XCD = b
    const int sl  = lid >> 3;              // 0..199
    const int mt  = sl & 7;
    const int nt  = sl >> 3;               // 0..24

    f32x4 acc[4][4];
    #pragma unroll
    for (int i = 0; i < 4; i++)
        #pragma unroll
        for (int j = 0; j < 4; j++) acc[i][j] = (f32x4){0.f, 0.f, 0.f, 0.f};

    // staging chunk map: issue0 ch=tid -> (r=tid>>2, slot j=tid&3); issue1 r+=64
    const int js = tid & 3;
    const int r0 = tid >> 2,  q0 = js ^ (r0 & 3) ^ ((r0 >> 2) & 3);
    const int r1 = r0 + 64,   q1 = js ^ (r1 & 3) ^ ((r1 >> 2) & 3);
    const unsigned short* ga0 = Abf + (size_t)(mt * 128 + r0) * KTOT + q0 * 8;
    const unsigned short* ga1 = Abf + (size_t)(mt * 128 + r1) * KTOT + q1 * 8;
    const int p0 = min(nt * 128 + r0, NPIX - 1);
    const int p1 = min(nt * 128 + r1, NPIX - 1);
    const int y0p = p0 / WWID, x0p = p0 - y0p * WWID;
    const int y1p = p1 / WWID, x1p = p1 - y1p * WWID;
    const unsigned short* gb0 = Xt + ((size_t)b * HPIX + y0p * HALO + x0p) * 128 + q0 * 8;
    const unsigned short* gb1 = Xt + ((size_t)b * HPIX + y1p * HALO + x1p) * 128 + q1 * 8;

    unsigned short* la0[2] = { &Ash[0][(wv * 64) * 8],       &Ash[1][(wv * 64) * 8] };
    unsigned short* la1[2] = { &Ash[0][(256 + wv * 64) * 8], &Ash[1][(256 + wv * 64) * 8] };
    unsigned short* lb0[2] = { &Bsh[0][(wv * 64) * 8],       &Bsh[1][(wv * 64) * 8] };
    unsigned short* lb1[2] = { &Bsh[0][(256 + wv * 64) * 8], &Bsh[1][(256 + wv * 64) * 8] };

    // frag-read slot offset (conflict-free): j' = lq ^ (lr&3) ^ ((lr>>2)&3)
    const int jj = lq ^ (lr & 3) ^ ((lr >> 2) & 3);

    // prefetch tile 0 into buf 0 (s=0 -> offB=0)
    cp16(ga0, la0[0]); cp16(ga1, la1[0]);
    cp16(gb0, lb0[0]); cp16(gb1, lb1[0]);

    int cur = 0;
    for (int kk = 0; kk < KTOT; kk += 32) {
        __syncthreads();                   // buf[cur] loads had a full compute phase of cover
        const int nk = kk + 32;
        if (nk < KTOT) {
            const int s  = nk >> 7;        // uniform: k-span never crosses a 128 boundary
            const int kh = s / 3, kw = s - 3 * kh;
            const int offB = (kh * HALO + kw) * 128 + (nk & 127);
            cp16(ga0 + nk, la0[cur ^ 1]); cp16(ga1 + nk, la1[cur ^ 1]);
            cp16(gb0 + offB, lb0[cur ^ 1]); cp16(gb1 + offB, lb1[cur ^ 1]);
        }
        short8 af[4], bfr[4];
        #pragma unroll
        for (int tm = 0; tm < 4; tm++) {
            const int row = wrow * 64 + tm * 16 + lr;
            af[tm] = *(const short8*)&Ash[cur][(row * 4 + jj) * 8];
        }
        #pragma unroll
        for (int tn = 0; tn < 4; tn++) {
            const int row = wcol * 64 + tn * 16 + lr;
            bfr[tn] = *(const short8*)&Bsh[cur][(row * 4 + jj) * 8];
        }
        #pragma unroll
        for (int tm = 0; tm < 4; tm++)
            #pragma unroll
            for (int tn = 0; tn < 4; tn++)
                acc[tm][tn] = __builtin_amdgcn_mfma_f32_16x16x32_bf16(
                    af[tm], bfr[tn], acc[tm][tn], 0, 0, 0);
        cur ^= 1;
    }

    // epilogue: rows m -> j = (lq&1)*4+reg, o_off = lq>>1
    const int j0 = (lq & 1) * 4;
    const int oo = lq >> 1;
    #pragma unroll
    for (int tm = 0; tm < 4; tm++) {
        const int o = mt * 16 + wrow * 8 + tm * 2 + oo;
        const float bo = bias[o];
        #pragma unroll
        for (int tn = 0; tn < 4; tn++) {
            const int p = nt * 128 + wcol * 64 + tn * 16 + lr;
            const f32x4 sv = *(const f32x4*)&Sws[((size_t)b * PPAD + p) * 8 + j0];
            const f32x4 a = acc[tm][tn];
            float part = a.x * sv.x + a.y * sv.y + a.z * sv.z + a.w * sv.w;
            float tot = part + __shfl_xor(part, 16);
            if ((lq & 1) == 0 && p < NPIX)
                out[((size_t)b * OUT_C + o) * NPIX + p] = tot + bo;
        }
    }
}

extern "C" void kernel_launch(void* const* d_in, const int* in_sizes, int n_in,
                              void* d_out, int out_size, void* d_ws, size_t ws_size,
                              hipStream_t stream) {
    const float* inputs = (const float*)d_in[0];
    const int*   mask   = (const int*)d_in[1];
    const float* Alpha  = (const float*)d_in[2];
    const float* wtmpl  = (const float*)d_in[3];
    const float* rw     = (const float*)d_in[4];
    const float* rb     = (const float*)d_in[5];
    const float* bias   = (const float*)d_in[6];
    const int*   ua     = (const int*)d_in[7];
    float* out = (float*)d_out;

    char* ws = (char*)d_ws;
    unsigned short* Xt  = (unsigned short*)ws;                  // 8*3364*128*2 = 6,889,472
    unsigned short* Abf = (unsigned short*)(ws + 6889472);      // 1024*1152*2  = 2,359,296
    float*          Sws = (float*)(ws + 9248768);               // 8*3200*8*4   =   819,200
    float*          xse = (float*)(ws + 10067968);              // 1024*4

    prep_kernel<<<1376, 256, 0, stream>>>(inputs, wtmpl, xse, Abf, Xt);
    s_kernel<<<dim3(13, NB), 256, 0, stream>>>(Alpha, mask, xse, rw, rb, ua, Sws);
    gemm_kernel<<<1600, 256, 0, stream>>>(Abf, Xt, Sws, bias, out);
}

// Round 7
// 167.800 us; speedup vs baseline: 1.4317x; 1.0486x over previous
//
#include <hip/hip_runtime.h>
#include <stdint.h>

#define IN_C   128
#define OUT_C  128
#define KTOT   1152      // IN_C*3*3
#define NG     8
#define NW     8
#define NB     8
#define HH     56
#define WWID   56
#define NPIX   3136
#define PPAD   3200
#define MTOT   1024      // OUT_C*NW
#define HALO   58        // 56 + zero border on each side
#define HPIX   (HALO*HALO)   // 3364

// k-order is SPATIAL-MAJOR: k' = s*128 + c, s = kh*3+kw.
// B gathered from zero-halo Xt[b][58*58][128c] bf16, staged via LDS.
// A pre-packed FRAGMENT-LINEAR: Apack[m16][kt][lq][lr][8e] so a wave's A-frag
// load is one contiguous 1KB global_load_dwordx4 (lane ln -> offset ln*16B);
// A never touches LDS (L1/L2-resident), halving LDS traffic vs R6.

typedef __attribute__((ext_vector_type(8))) short short8;
typedef __attribute__((ext_vector_type(8))) unsigned short ushort8;
typedef __attribute__((ext_vector_type(4))) float f32x4;

__device__ __forceinline__ unsigned short f2bf(float f) {
    unsigned u = __float_as_uint(f);
    u += 0x7FFF + ((u >> 16) & 1);          // round-to-nearest-even
    return (unsigned short)(u >> 16);
}

__device__ __forceinline__ void cp16(const unsigned short* g, unsigned short* l) {
    __builtin_amdgcn_global_load_lds(
        (const __attribute__((address_space(1))) unsigned int*)g,
        (__attribute__((address_space(3))) unsigned int*)l,
        16, 0, 0);
}

// ---------- 1) fused prep: gap (0..1023) | tconv/pack (1024..1151) | transpose (1152..1375) ----------
__global__ __launch_bounds__(256) void prep_kernel(const float* __restrict__ in,
                                                   const float* __restrict__ T,
                                                   float* __restrict__ xse,
                                                   unsigned short* __restrict__ Apack,
                                                   unsigned short* __restrict__ Xt) {
    __shared__ __align__(16) unsigned char smem[36864];   // 36 KB
    const int blk = blockIdx.x;
    const int t = threadIdx.x;

    if (blk < 1024) {
        // ---- global average pool: xse[b,c] ----
        const float* src = in + (size_t)blk * NPIX;
        float s = 0.f;
        for (int i = t; i < NPIX / 4; i += 256) {
            float4 v = ((const float4*)src)[i];
            s += v.x + v.y + v.z + v.w;
        }
        #pragma unroll
        for (int off = 32; off; off >>= 1) s += __shfl_down(s, off);
        float* ws4 = (float*)smem;
        if ((t & 63) == 0) ws4[t >> 6] = s;
        __syncthreads();
        if (t == 0)
            xse[blk] = (ws4[0] + ws4[1] + ws4[2] + ws4[3]) * (1.0f / (float)NPIX);
        return;
    }
    if (blk < 1152) {
        // ---- tconv+pack: block per o. T[o][k][j] slab -> LDS -> fragment-linear Apack.
        // Apack elem: [m16 = (o*8+j)>>4][kt][lq][lr = (o&1)*8+j][e] = A[o*8+j][kt*32+lq*8+e]
        //   with A[m][k'= s*128+c] = T[(o*1152 + c*9 + s)*8 + j]
        float* lf = (float*)smem;                    // 9216 floats = 36 KB
        const int o = blk - 1024;
        const float* To = T + (size_t)o * 9216;
        #pragma unroll
        for (int it = 0; it < 9; it++) {
            const int f = it * 256 + t;              // 0..2303 float4 units
            const float4 v = ((const float4*)To)[f];
            *(float4*)&lf[f * 4] = v;
        }
        __syncthreads();
        const int m16b = o >> 1;
        const int lrb = (o & 1) * 8;
        #pragma unroll
        for (int it = 0; it < 5; it++) {
            const int ch = it * 256 + t;             // 0..1151: ch = kc*8 + j
            if (ch < 1152) {
                const int j = ch & 7, kc = ch >> 3;  // kc = k-octet 0..143
                const int s = kc >> 4, c0 = (kc & 15) << 3;
                const int kt = kc >> 2, lq = kc & 3;
                ushort8 v;
                #pragma unroll
                for (int i = 0; i < 8; i++)
                    v[i] = f2bf(lf[((c0 + i) * 9 + s) * 8 + j]);
                const size_t off = ((((size_t)m16b * 36 + kt) * 4 + lq) * 16 + lrb + j) * 8;
                *(ushort8*)&Apack[off] = v;
            }
        }
        return;
    }
    // ---- transpose: in[b][c][y][x] fp32 -> Xt[b][(y+1)*58+(x+1)][c] bf16, zero halo ----
    unsigned short* tile = (unsigned short*)smem;    // 32 KB, [c][pix 0..112)
    const int idx = blk - 1152;                      // 0..223
    const int yt = idx % 28;
    const int b  = idx / 28;
    const int y0 = yt * 2;

    #pragma unroll
    for (int it = 0; it < 14; it++) {
        const int f = it * 256 + t;
        const int c = f / 28;
        const int rem = f - c * 28;
        const int y = rem / 14;
        const int x4 = rem - y * 14;
        const float4 v = *(const float4*)(in + ((size_t)(b * IN_C + c)) * NPIX
                                          + (y0 + y) * WWID + x4 * 4);
        unsigned short bf0 = f2bf(v.x), bf1 = f2bf(v.y), bf2 = f2bf(v.z), bf3 = f2bf(v.w);
        const int ppb = (y * WWID + x4 * 4) ^ (((c >> 3) & 15) << 2);
        uint2 pk;
        pk.x = (unsigned)bf0 | ((unsigned)bf1 << 16);
        pk.y = (unsigned)bf2 | ((unsigned)bf3 << 16);
        *(uint2*)&tile[c * 128 + ppb] = pk;
    }
    __syncthreads();

    #pragma unroll
    for (int it = 0; it < 7; it++) {
        const int ch = it * 256 + t;
        const int oct = ch & 15;
        const int pp = ch >> 4;
        const int sw = oct << 2;
        ushort8 v;
        #pragma unroll
        for (int i = 0; i < 8; i++)
            v[i] = tile[(oct * 8 + i) * 128 + (pp ^ sw)];
        const int y2 = (pp >= WWID) ? 1 : 0;
        const int xg = pp - y2 * WWID;
        const size_t hp = (size_t)b * HPIX + (y0 + y2 + 1) * HALO + (xg + 1);
        *(ushort8*)&Xt[hp * 128 + oct * 8] = v;
    }

    if (t < 64) {   // halo columns xx=0,57 for this block's two rows
        const int pi = t >> 4, oct = t & 15;
        const int yy = y0 + 1 + (pi >> 1);
        const int xx = (pi & 1) * 57;
        *(ushort8*)&Xt[((size_t)b * HPIX + yy * HALO + xx) * 128 + oct * 8] =
            (ushort8){0, 0, 0, 0, 0, 0, 0, 0};
    }
    if (yt == 0 || yt == 27) {   // halo rows yy=0 / 57
        const int yy = (yt == 0) ? 0 : 57;
        #pragma unroll
        for (int it = 0; it < 4; it++) {
            const int ch = it * 256 + t;
            if (ch < 928) {
                const int xx = ch >> 4, oct = ch & 15;
                *(ushort8*)&Xt[((size_t)b * HPIX + yy * HALO + xx) * 128 + oct * 8] =
                    (ushort8){0, 0, 0, 0, 0, 0, 0, 0};
            }
        }
    }
}

// ---------- 2) s_kernel (routing fused): s[b][p][j] = sum_g probs[b,g,p] * r[b,g*8+j] ----------
__global__ __launch_bounds__(256) void s_kernel(const float* __restrict__ Alpha,
                                                const int* __restrict__ mask,
                                                const float* __restrict__ xse,
                                                const float* __restrict__ rw,
                                                const float* __restrict__ rb,
                                                const int* __restrict__ use_alpha,
                                                float* __restrict__ Sws) {
    const int b = blockIdx.y;
    const int t = threadIdx.x;
    const int p = blockIdx.x * 256 + t;
    __shared__ float xs[IN_C];
    __shared__ float rsh[64];
    if (t < IN_C) xs[t] = xse[b * IN_C + t];
    __syncthreads();
    if (t < 64) {
        float acc = rb[t];
        #pragma unroll 8
        for (int c = 0; c < IN_C; c++) acc += xs[c] * rw[t * IN_C + c];
        rsh[t] = 0.25f / (1.0f + expf(-acc));        // 2*sigmoid/8
    }
    __syncthreads();
    if (p >= PPAD) return;
    float sj[8] = {0, 0, 0, 0, 0, 0, 0, 0};
    if (p < NPIX) {
        float pr[8];
        if (use_alpha[0]) {
            float a[8], m = -1e30f;
            #pragma unroll
            for (int g = 0; g < 8; g++) {
                a[g] = Alpha[((size_t)(b * NG + g)) * NPIX + p];
                m = fmaxf(m, a[g]);
            }
            float sum = 0.f;
            #pragma unroll
            for (int g = 0; g < 8; g++) { pr[g] = expf(a[g] - m); sum += pr[g]; }
            float inv = 1.f / sum;
            #pragma unroll
            for (int g = 0; g < 8; g++) pr[g] *= inv;
        } else {
            int mg = mask[(size_t)b * NPIX + p];
            #pragma unroll
            for (int g = 0; g < 8; g++) pr[g] = (g == mg) ? 1.f : 0.f;
        }
        #pragma unroll
        for (int g = 0; g < 8; g++)
            #pragma unroll
            for (int j = 0; j < 8; j++) sj[j] += pr[g] * rsh[g * 8 + j];
    }
    float* dst = Sws + ((size_t)b * PPAD + p) * 8;
    *(f32x4*)dst = (f32x4){sj[0], sj[1], sj[2], sj[3]};
    *(f32x4*)(dst + 4) = (f32x4){sj[4], sj[5], sj[6], sj[7]};
}

// ---------- 3) main GEMM + blend epilogue ----------
// B via global_load_lds (2 x 8 KB dbuf, 1 barrier/k32); A-frags direct
// global->VGPR from fragment-linear Apack (coalesced 1KB/wave), reg ping-pong.
__global__ __launch_bounds__(256) void gemm_kernel(const unsigned short* __restrict__ Apack,
                                                   const unsigned short* __restrict__ Xt,
                                                   const float* __restrict__ Sws,
                                                   const float* __restrict__ bias,
                                                   float* __restrict__ out) {
    __shared__ __align__(16) unsigned short Bsh[2][512 * 8];   // 2 x 8 KB
    const int tid = threadIdx.x;
    const int wv = tid >> 6, ln = tid & 63;
    const int lq = ln >> 4, lr = ln & 15;
    const int wrow = wv >> 1, wcol = wv & 1;

    const int lid = blockIdx.x;            // 0..1599
    const int b   = lid & 7;               // XCD = b
    const int sl  = lid >> 3;              // 0..199
    const int mt  = sl & 7;
    const int nt  = sl >> 3;               // 0..24

    f32x4 acc[4][4];
    #pragma unroll
    for (int i = 0; i < 4; i++)
        #pragma unroll
        for (int j = 0; j < 4; j++) acc[i][j] = (f32x4){0.f, 0.f, 0.f, 0.f};

    // B staging: chunk (r, slot js) holds octet q = js ^ (r&3) ^ ((r>>2)&3)
    const int js = tid & 3;
    const int r0 = tid >> 2,  q0 = js ^ (r0 & 3) ^ ((r0 >> 2) & 3);
    const int r1 = r0 + 64,   q1 = js ^ (r1 & 3) ^ ((r1 >> 2) & 3);
    const int p0 = min(nt * 128 + r0, NPIX - 1);
    const int p1 = min(nt * 128 + r1, NPIX - 1);
    const int y0p = p0 / WWID, x0p = p0 - y0p * WWID;
    const int y1p = p1 / WWID, x1p = p1 - y1p * WWID;
    const unsigned short* gb0 = Xt + ((size_t)b * HPIX + y0p * HALO + x0p) * 128 + q0 * 8;
    const unsigned short* gb1 = Xt + ((size_t)b * HPIX + y1p * HALO + x1p) * 128 + q1 * 8;
    unsigned short* lb0[2] = { &Bsh[0][(wv * 64) * 8],       &Bsh[1][(wv * 64) * 8] };
    unsigned short* lb1[2] = { &Bsh[0][(256 + wv * 64) * 8], &Bsh[1][(256 + wv * 64) * 8] };

    // A fragment-linear pointers: per tm, wave reads 1KB contiguous at kt*1KB stride
    const unsigned short* gaw[4];
    #pragma unroll
    for (int tm = 0; tm < 4; tm++) {
        const int m16 = mt * 8 + wrow * 4 + tm;
        gaw[tm] = Apack + ((size_t)m16 * 36 * 64 + ln) * 8;
    }

    // frag-read slot for B: j' = lq ^ (lr&3) ^ ((lr>>2)&3)
    const int jj = lq ^ (lr & 3) ^ ((lr >> 2) & 3);

    // prologue: B tile 0 -> buf0; A frags kt=0 -> afA
    cp16(gb0, lb0[0]); cp16(gb1, lb1[0]);
    short8 afA[4], afB[4];
    #pragma unroll
    for (int tm = 0; tm < 4; tm++) afA[tm] = *(const short8*)(gaw[tm]);

    #pragma unroll 1
    for (int it = 0; it < 18; it++) {
        const int kk = it * 64;
        // ---- half 0: compute kk (buf0, afA); prefetch kk+32 (buf1, afB) ----
        __syncthreads();
        {
            const int nk = kk + 32;                    // always < KTOT
            const int s  = nk >> 7;
            const int kh = s / 3, kw = s - 3 * kh;
            const int offB = (kh * HALO + kw) * 128 + (nk & 127);
            cp16(gb0 + offB, lb0[1]); cp16(gb1 + offB, lb1[1]);
            #pragma unroll
            for (int tm = 0; tm < 4; tm++)
                afB[tm] = *(const short8*)(gaw[tm] + (size_t)(nk >> 5) * 512);
        }
        {
            short8 bfr[4];
            #pragma unroll
            for (int tn = 0; tn < 4; tn++) {
                const int row = wcol * 64 + tn * 16 + lr;
                bfr[tn] = *(const short8*)&Bsh[0][(row * 4 + jj) * 8];
            }
            #pragma unroll
            for (int tm = 0; tm < 4; tm++)
                #pragma unroll
                for (int tn = 0; tn < 4; tn++)
                    acc[tm][tn] = __builtin_amdgcn_mfma_f32_16x16x32_bf16(
                        afA[tm], bfr[tn], acc[tm][tn], 0, 0, 0);
        }
        // ---- half 1: compute kk+32 (buf1, afB); prefetch kk+64 (buf0, afA) ----
        __syncthreads();
        {
            const int nk = kk + 64;
            if (nk < KTOT) {
                const int s  = nk >> 7;
                const int kh = s / 3, kw = s - 3 * kh;
                const int offB = (kh * HALO + kw) * 128 + (nk & 127);
                cp16(gb0 + offB, lb0[0]); cp16(gb1 + offB, lb1[0]);
                #pragma unroll
                for (int tm = 0; tm < 4; tm++)
                    afA[tm] = *(const short8*)(gaw[tm] + (size_t)(nk >> 5) * 512);
            }
        }
        {
            short8 bfr[4];
            #pragma unroll
            for (int tn = 0; tn < 4; tn++) {
                const int row = wcol * 64 + tn * 16 + lr;
                bfr[tn] = *(const short8*)&Bsh[1][(row * 4 + jj) * 8];
            }
            #pragma unroll
            for (int tm = 0; tm < 4; tm++)
                #pragma unroll
                for (int tn = 0; tn < 4; tn++)
                    acc[tm][tn] = __builtin_amdgcn_mfma_f32_16x16x32_bf16(
                        afB[tm], bfr[tn], acc[tm][tn], 0, 0, 0);
        }
    }

    // epilogue: rows m -> j = (lq&1)*4+reg, o_off = lq>>1
    const int j0 = (lq & 1) * 4;
    const int oo = lq >> 1;
    #pragma unroll
    for (int tm = 0; tm < 4; tm++) {
        const int o = mt * 16 + wrow * 8 + tm * 2 + oo;
        const float bo = bias[o];
        #pragma unroll
        for (int tn = 0; tn < 4; tn++) {
            const int p = nt * 128 + wcol * 64 + tn * 16 + lr;
            const f32x4 sv = *(const f32x4*)&Sws[((size_t)b * PPAD + p) * 8 + j0];
            const f32x4 a = acc[tm][tn];
            float part = a.x * sv.x + a.y * sv.y + a.z * sv.z + a.w * sv.w;
            float tot = part + __shfl_xor(part, 16);
            if ((lq & 1) == 0 && p < NPIX)
                out[((size_t)b * OUT_C + o) * NPIX + p] = tot + bo;
        }
    }
}

extern "C" void kernel_launch(void* const* d_in, const int* in_sizes, int n_in,
                              void* d_out, int out_size, void* d_ws, size_t ws_size,
                              hipStream_t stream) {
    const float* inputs = (const float*)d_in[0];
    const int*   mask   = (const int*)d_in[1];
    const float* Alpha  = (const float*)d_in[2];
    const float* wtmpl  = (const float*)d_in[3];
    const float* rw     = (const float*)d_in[4];
    const float* rb     = (const float*)d_in[5];
    const float* bias   = (const float*)d_in[6];
    const int*   ua     = (const int*)d_in[7];
    float* out = (float*)d_out;

    char* ws = (char*)d_ws;
    unsigned short* Xt  = (unsigned short*)ws;                  // 8*3364*128*2 = 6,889,472
    unsigned short* Apk = (unsigned short*)(ws + 6889472);      // 1024*1152*2  = 2,359,296
    float*          Sws = (float*)(ws + 9248768);               // 8*3200*8*4   =   819,200
    float*          xse = (float*)(ws + 10067968);              // 1024*4

    prep_kernel<<<1376, 256, 0, stream>>>(inputs, wtmpl, xse, Apk, Xt);
    s_kernel<<<dim3(13, NB), 256, 0, stream>>>(Alpha, mask, xse, rw, rb, ua, Sws);
    gemm_kernel<<<1600, 256, 0, stream>>>(Apk, Xt, Sws, bias, out);
}